// Round 1
// 612.941 us; speedup vs baseline: 1.1750x; 1.1750x over previous
//
#include <hip/hip_runtime.h>

// Problem constants
#define NMAT 50
#define BATCH 128
#define FDIM 1024
#define HDIM 4096
#define ROWS 6400            // BATCH*NMAT
#define PSIZE 320000         // BATCH*NMAT*NMAT
#define HINF 1e18

// ws layout (bytes):
//   Mpart : [0, 10240000)           fp64 [4][6400][50] split-K partials;
//                                   partial 0 overwritten with psi64 by sinkhorn
//   Xh/Xl : packed split-bf16 X     [50 mt][32 k0b][4 kg][128 m][8] each 13.1 MB
//   W1h/l : packed split-bf16 W1^T  [32 nt][32 k0b][4 kg][128 n][8] each 8.4 MB
//   hbuf  : fp32 [max_rows][4096]   chunked to fit remaining ws
#define WS_M_OFF   0
#define WS_XH_OFF  10240000LL
#define WS_XL_OFF  23347200LL
#define WS_W1H_OFF 36454400LL
#define WS_W1L_OFF 44843008LL
#define WS_H_OFF   53231616LL
#define WS_MIN     (WS_H_OFF + 128LL * HDIM * 4)   // ~55.3 MB

typedef __bf16 bf16x8 __attribute__((ext_vector_type(8)));
typedef float f32x4 __attribute__((ext_vector_type(4)));
typedef unsigned short u16;

__device__ __forceinline__ float bf16_to_f32(unsigned short h) {
  return __uint_as_float(((unsigned int)h) << 16);
}
__device__ __forceinline__ unsigned short f32_to_bf16(float f) {
  unsigned int u = __float_as_uint(f);
  u += 0x7FFFu + ((u >> 16) & 1u);   // RNE
  return (unsigned short)(u >> 16);
}

// async global->LDS, 16B per lane; LDS dest = wave-uniform base + lane*16
__device__ __forceinline__ void gload16(const u16* g, u16* l) {
  __builtin_amdgcn_global_load_lds(
      (const __attribute__((address_space(1))) unsigned int*)g,
      (__attribute__((address_space(3))) unsigned int*)l, 16, 0, 0);
}

// ---------------- pre-pass: X fp32 -> packed split-bf16 ---------------------
// out layout: [mt][k0b][kg][m][8] elems; blockIdx = mt*32 + k0b.
// Reads 32B/lane (stride-4KB, sibling halves L1-covered within block);
// writes fully coalesced 16B/lane.
__global__ __launch_bounds__(256) void convert_x(
    const float* __restrict__ X, u16* __restrict__ Xh, u16* __restrict__ Xl) {
  int t = threadIdx.x;
  int mt = blockIdx.x >> 5, k0b = blockIdx.x & 31;
  size_t outbase = (size_t)blockIdx.x * 4096;
#pragma unroll
  for (int it = 0; it < 2; ++it) {
    int idx = t + it * 256;
    int m = idx & 127, kg = idx >> 7;
    const float* src = X + (size_t)(mt * 128 + m) * FDIM + k0b * 32 + kg * 8;
    float4 v0 = *(const float4*)src;
    float4 v1 = *(const float4*)(src + 4);
    float f[8] = {v0.x, v0.y, v0.z, v0.w, v1.x, v1.y, v1.z, v1.w};
    unsigned short h[8], l[8];
#pragma unroll
    for (int j = 0; j < 8; ++j) {
      h[j] = f32_to_bf16(f[j]);
      l[j] = f32_to_bf16(f[j] - bf16_to_f32(h[j]));
    }
    uint4 hv, lv;
    hv.x = h[0] | ((unsigned)h[1] << 16); hv.y = h[2] | ((unsigned)h[3] << 16);
    hv.z = h[4] | ((unsigned)h[5] << 16); hv.w = h[6] | ((unsigned)h[7] << 16);
    lv.x = l[0] | ((unsigned)l[1] << 16); lv.y = l[2] | ((unsigned)l[3] << 16);
    lv.z = l[4] | ((unsigned)l[5] << 16); lv.w = l[6] | ((unsigned)l[7] << 16);
    size_t off = outbase + (size_t)(kg * 128 + m) * 8;
    *(uint4*)&Xh[off] = hv;
    *(uint4*)&Xl[off] = lv;
  }
}

// ---------------- pre-pass: W1 fp32 -> transposed packed split-bf16 ---------
// out layout: [nt][k0b][kg][n][8]; blockIdx = nt*32 + k0b.
// Reads coalesced along n (the same transposed gather gemm1 used to do 32x);
// writes fully coalesced.
__global__ __launch_bounds__(256) void convert_w1(
    const float* __restrict__ W1, u16* __restrict__ Wh, u16* __restrict__ Wl) {
  int t = threadIdx.x;
  int nt = blockIdx.x >> 5, k0b = blockIdx.x & 31;
  size_t outbase = (size_t)blockIdx.x * 4096;
#pragma unroll
  for (int it = 0; it < 2; ++it) {
    int idx = t + it * 256;
    int n = idx & 127, kg = idx >> 7;
    float f[8];
#pragma unroll
    for (int j = 0; j < 8; ++j)
      f[j] = W1[(size_t)(k0b * 32 + kg * 8 + j) * HDIM + nt * 128 + n];
    unsigned short h[8], l[8];
#pragma unroll
    for (int j = 0; j < 8; ++j) {
      h[j] = f32_to_bf16(f[j]);
      l[j] = f32_to_bf16(f[j] - bf16_to_f32(h[j]));
    }
    uint4 hv, lv;
    hv.x = h[0] | ((unsigned)h[1] << 16); hv.y = h[2] | ((unsigned)h[3] << 16);
    hv.z = h[4] | ((unsigned)h[5] << 16); hv.w = h[6] | ((unsigned)h[7] << 16);
    lv.x = l[0] | ((unsigned)l[1] << 16); lv.y = l[2] | ((unsigned)l[3] << 16);
    lv.z = l[4] | ((unsigned)l[5] << 16); lv.w = l[6] | ((unsigned)l[7] << 16);
    size_t off = outbase + (size_t)(kg * 128 + n) * 8;
    *(uint4*)&Wh[off] = hv;
    *(uint4*)&Wl[off] = lv;
  }
}

// ---------------- GEMM1 (split-bf16 MFMA): h = leaky(x @ W1 + b1) -----------
// Inputs pre-split/pre-packed; staging is pure global_load_lds width-16
// (zero VALU conversion in the hot loop). 128x128 tile, BK=32, 4 waves,
// 48 MFMA per k-step. LDS [kg][idx][8] matches both the linear gload_lds
// dest order and the fragment-read order (conflict-free, as before).
// Per-accumulator term order hh,hl,lh per k-step — bit-identical numerics
// to the previous in-loop-conversion version.
__global__ __launch_bounds__(256) void gemm1_mfma(
    const u16* __restrict__ Ah_, const u16* __restrict__ Al_,
    const u16* __restrict__ Bh_, const u16* __restrict__ Bl_,
    const float* __restrict__ b1,
    float* __restrict__ Hout,          // chunk base [rows][4096] fp32
    int mt0) {                         // global m-tile offset of this chunk
  __shared__ __align__(16) u16 Ah[4096];
  __shared__ __align__(16) u16 Al[4096];
  __shared__ __align__(16) u16 Bh[4096];
  __shared__ __align__(16) u16 Bl[4096];
  int t = threadIdx.x;
  int wave = t >> 6, lane = t & 63;
  int nt = blockIdx.x & 31;      // 4096/128 n-tiles
  int mtl = blockIdx.x >> 5;     // m-tile local to chunk
  int wm = wave >> 1, wn = wave & 1;
  int fr = lane & 15, fg = lane >> 4;

  f32x4 acc[4][4];
#pragma unroll
  for (int i = 0; i < 4; ++i)
#pragma unroll
    for (int j = 0; j < 4; ++j) acc[i][j] = (f32x4){0.f, 0.f, 0.f, 0.f};

  const u16* pAh = Ah_ + (size_t)(mt0 + mtl) * 32 * 4096;
  const u16* pAl = Al_ + (size_t)(mt0 + mtl) * 32 * 4096;
  const u16* pBh = Bh_ + (size_t)nt * 32 * 4096;
  const u16* pBl = Bl_ + (size_t)nt * 32 * 4096;
  int so = wave * 1024 + lane * 8;   // per-lane src offset (elems), call 0
  int ld = wave * 1024;              // wave-uniform LDS dest (elems)

  for (int k0b = 0; k0b < 32; ++k0b) {
    __syncthreads();                 // previous-iter fragment reads done
    size_t sb = (size_t)k0b * 4096;
    gload16(pAh + sb + so,       &Ah[ld]);
    gload16(pAh + sb + so + 512, &Ah[ld + 512]);
    gload16(pAl + sb + so,       &Al[ld]);
    gload16(pAl + sb + so + 512, &Al[ld + 512]);
    gload16(pBh + sb + so,       &Bh[ld]);
    gload16(pBh + sb + so + 512, &Bh[ld + 512]);
    gload16(pBl + sb + so,       &Bl[ld]);
    gload16(pBl + sb + so + 512, &Bl[ld + 512]);
    __syncthreads();                 // vmcnt(0) drained by compiler before barrier
    // ---- fragments + MFMA ----
    bf16x8 ah[4], al[4], bh[4], bl[4];
#pragma unroll
    for (int i = 0; i < 4; ++i) {
      int arow = (fg * 128 + wm * 64 + i * 16 + fr) * 8;
      ah[i] = *(const bf16x8*)&Ah[arow];
      al[i] = *(const bf16x8*)&Al[arow];
      int brow = (fg * 128 + wn * 64 + i * 16 + fr) * 8;
      bh[i] = *(const bf16x8*)&Bh[brow];
      bl[i] = *(const bf16x8*)&Bl[brow];
    }
#pragma unroll
    for (int i = 0; i < 4; ++i)
#pragma unroll
      for (int j = 0; j < 4; ++j)
        acc[i][j] = __builtin_amdgcn_mfma_f32_16x16x32_bf16(ah[i], bh[j], acc[i][j], 0, 0, 0);
#pragma unroll
    for (int i = 0; i < 4; ++i)
#pragma unroll
      for (int j = 0; j < 4; ++j)
        acc[i][j] = __builtin_amdgcn_mfma_f32_16x16x32_bf16(ah[i], bl[j], acc[i][j], 0, 0, 0);
#pragma unroll
    for (int i = 0; i < 4; ++i)
#pragma unroll
      for (int j = 0; j < 4; ++j)
        acc[i][j] = __builtin_amdgcn_mfma_f32_16x16x32_bf16(al[i], bh[j], acc[i][j], 0, 0, 0);
  }

  // Epilogue: col=lane&15, row=(lane>>4)*4+reg [m89-verified]
  int colb = nt * 128 + wn * 64 + fr;
  int rowb = mtl * 128 + wm * 64 + fg * 4;
#pragma unroll
  for (int j = 0; j < 4; ++j) {
    float bias = b1[colb + j * 16];
#pragma unroll
    for (int i = 0; i < 4; ++i)
#pragma unroll
      for (int r = 0; r < 4; ++r) {
        float v = acc[i][j][r] + bias;
        v = v >= 0.0f ? v : 0.01f * v;
        Hout[(size_t)(rowb + i * 16 + r) * HDIM + colb + j * 16] = v;
      }
  }
}

// ---------------- GEMM2: Mpart[kz] = h @ W2 (fp64, split-K=4) ---------------
__global__ __launch_bounds__(256) void gemm2_kernel(
    const float* __restrict__ hchunk,        // chunk base [rows][4096] fp32
    const float* __restrict__ W2,            // [4096][50] fp32
    double* __restrict__ Mpart,              // [4][6400][50]
    int row0) {
  __shared__ __align__(16) float hs[32 * 64];
  __shared__ float w2s[64 * 52];
  int t = threadIdx.x;
  int c = t & 63, g = t >> 6;                // rows g, g+4, ..., g+28
  int kz = blockIdx.y;
  double acc[8] = {0, 0, 0, 0, 0, 0, 0, 0};
  const float* hbase = hchunk + (size_t)blockIdx.x * 32 * HDIM;

  for (int k0 = kz * 1024; k0 < kz * 1024 + 1024; k0 += 64) {
    __syncthreads();
    {
      int row = t >> 3, seg = (t & 7) * 8;
      const float4* src = (const float4*)(hbase + (size_t)row * HDIM + k0 + seg);
      float4 v0 = src[0], v1 = src[1];
      float4* dst = (float4*)(hs + row * 64 + seg);
      dst[0] = v0; dst[1] = v1;
    }
    for (int idx = t; idx < 3200; idx += 256) {     // 64 k x 50 c, coalesced
      int cc = idx % 50, kk = idx / 50;
      w2s[kk * 52 + cc] = W2[(size_t)k0 * NMAT + idx];
    }
    __syncthreads();
    if (c < NMAT) {
#pragma unroll 4
      for (int kk = 0; kk < 64; kk += 2) {
        double w0 = (double)w2s[kk * 52 + c];
        double w1 = (double)w2s[kk * 52 + 52 + c];
#pragma unroll
        for (int i = 0; i < 8; ++i) {
          float2 hv = *(const float2*)&hs[(g + i * 4) * 64 + kk];   // broadcast
          acc[i] = fma((double)hv.x, w0, acc[i]);
          acc[i] = fma((double)hv.y, w1, acc[i]);
        }
      }
    }
  }
  if (c < NMAT) {
    double* Mout = Mpart + (size_t)kz * PSIZE;
#pragma unroll
    for (int i = 0; i < 8; ++i)
      Mout[(size_t)(row0 + blockIdx.x * 32 + g + i * 4) * NMAT + c] = acc[i];
  }
}

// ---------------- Sinkhorn (fp64): merge 4 partials, P=exp(leaky(M+b2)), ----
// 5x row/col norm. Writes psi64 into Mpart[0] region (block-local, safe).
__global__ __launch_bounds__(64) void sinkhorn_kernel(
    double* __restrict__ Mpart, const float* __restrict__ b2,
    float* __restrict__ out_psi, float* __restrict__ out_X) {
  int b = blockIdx.x, lane = threadIdx.x;
  __shared__ double P[2500];
  __shared__ double rs[50];
  const size_t base = (size_t)b * 2500;
  for (int e = lane; e < 2500; e += 64) {
    double m = Mpart[base + e] + Mpart[PSIZE + base + e] +
               Mpart[2 * PSIZE + base + e] + Mpart[3 * PSIZE + base + e];
    m += (double)b2[e % 50];
    m = m >= 0.0 ? m : 0.01 * m;      // leaky_relu in fp64
    P[e] = exp(m);                    // TAU = 1.0
  }
  __syncthreads();
  for (int it = 0; it < 5; ++it) {
    if (lane < 50) { double s = 0; for (int j = 0; j < 50; ++j) s += P[lane * 50 + j]; rs[lane] = s; }
    __syncthreads();
    for (int e = lane; e < 2500; e += 64) P[e] /= rs[e / 50];   // axis=2
    __syncthreads();
    if (lane < 50) { double s = 0; for (int r = 0; r < 50; ++r) s += P[r * 50 + lane]; rs[lane] = s; }
    __syncthreads();
    for (int e = lane; e < 2500; e += 64) P[e] /= rs[e % 50];   // axis=1
    __syncthreads();
  }
  for (int e = lane; e < 2500; e += 64) {
    double pv = P[e];
    Mpart[base + e] = pv;             // psi64 in-place (partial-0 region)
    float f = (float)pv;
    out_psi[base + e] = f;
    out_X[base + e] = f;              // ALPHA=1.0 => X == psi exactly
  }
}

// ---------------- Hungarian (exact replica of the reference's algorithm, ----
// including its dead-minv behavior), fp64, one wave per batch. FP32 outputs.
__global__ __launch_bounds__(64) void hungarian_kernel(
    const double* __restrict__ psi64, float* __restrict__ out_perms,
    float* __restrict__ out_dist) {
  int b = blockIdx.x, lane = threadIdx.x;
  __shared__ double cost[2500];
  __shared__ double u[51];
  __shared__ int p[51];
  __shared__ int wayl[51];
  const double* P = psi64 + (size_t)b * 2500;
  for (int e = lane; e < 2500; e += 64) cost[e] = -P[e];
  if (lane < 51) { u[lane] = 0.0; p[lane] = 0; }
  __syncthreads();
  double v = 0.0;                      // v[lane+1]
  bool lactive = lane < NMAT;

  for (int i = 1; i <= NMAT; ++i) {
    bool used = false;
    int way = 0;
    int j0 = 0, j1 = 0;
    for (int guard = 0; guard < 64; ++guard) {   // defensive cap (normally <=51)
      if (lane == j0 - 1) used = true;           // used[j0] = True (j0>=1)
      int i0 = (j0 == 0) ? i : p[j0];
      double ui0 = u[i0];
      double cand = HINF;
      if (lactive && !used) {
        cand = cost[(i0 - 1) * NMAT + lane] - ui0 - v;
        way = j0;                                // way set for ALL free cols (dead-minv)
      }
      double m = cand;
#pragma unroll
      for (int s = 32; s > 0; s >>= 1) {
        double o = __shfl_xor(m, s, 64);
        m = (o < m) ? o : m;
      }
      unsigned long long bal = __ballot(cand == m);
      j1 = (int)__builtin_ctzll(bal) + 1;        // np.argmin tie-break: lowest j
      double delta = m;
      __syncthreads();
      if (used) { v -= delta; u[p[lane + 1]] += delta; }   // distinct rows, no race
      if (lane == 63) u[i] += delta;                       // j=0 column: p[0]=i
      __syncthreads();
      j0 = j1;
      if (p[j0] == 0) break;
    }
    if (lactive) wayl[lane + 1] = way;
    __syncthreads();
    if (lane == 0) {                   // augment (serial, path <= 50)
      int j = j1;
      while (j != 0) {
        int jw = wayl[j];
        p[j] = (jw == 0) ? i : p[jw];
        j = jw;
      }
    }
    __syncthreads();
  }

  // perms one-hot + dist (fp32 outputs)
  size_t pbase = (size_t)b * 2500;
  for (int e = lane; e < 2500; e += 64) out_perms[pbase + e] = 0.0f;
  __syncthreads();
  double val = 0.0;
  if (lactive) {
    int row = p[lane + 1] - 1;
    if (row < 0) row = 0;              // defensive clamp (provably unreachable)
    if (row > 49) row = 49;
    out_perms[pbase + (size_t)row * NMAT + lane] = 1.0f;
    val = P[(size_t)row * NMAT + lane];
  }
#pragma unroll
  for (int s = 32; s > 0; s >>= 1) val += __shfl_xor(val, s, 64);
  if (lane == 0) out_dist[b] = (float)(val / (double)NMAT);
}

// ---------------------------------------------------------------------------
extern "C" void kernel_launch(void* const* d_in, const int* in_sizes, int n_in,
                              void* d_out, int out_size, void* d_ws, size_t ws_size,
                              hipStream_t stream) {
  const float* x  = (const float*)d_in[0];   // fp32 per the reference dtypes
  const float* W1 = (const float*)d_in[1];
  const float* b1 = (const float*)d_in[2];
  const float* W2 = (const float*)d_in[3];
  const float* b2 = (const float*)d_in[4];
  float* out = (float*)d_out;                // outputs float32 (round-8/11 finding)
  float* out_psi   = out;
  float* out_perms = out + PSIZE;
  float* out_X     = out + 2 * PSIZE;
  float* out_dist  = out + 3 * PSIZE;

  if (ws_size < (size_t)WS_MIN) return;

  char* ws = (char*)d_ws;
  double* Mpart = (double*)(ws + WS_M_OFF);
  u16* Xh  = (u16*)(ws + WS_XH_OFF);
  u16* Xl  = (u16*)(ws + WS_XL_OFF);
  u16* W1h = (u16*)(ws + WS_W1H_OFF);
  u16* W1l = (u16*)(ws + WS_W1L_OFF);
  float* hbuf = (float*)(ws + WS_H_OFF);
  long long avail = (long long)ws_size - WS_H_OFF;
  int max_rows = (int)(avail / (HDIM * 4));
  max_rows = (max_rows / 128) * 128;
  if (max_rows > ROWS) max_rows = ROWS;

  // one-time split-bf16 conversion + packing (replaces per-k-step VALU work)
  hipLaunchKernelGGL(convert_x, dim3(1600), dim3(256), 0, stream, x, Xh, Xl);
  hipLaunchKernelGGL(convert_w1, dim3(1024), dim3(256), 0, stream, W1, W1h, W1l);

  for (int r0 = 0; r0 < ROWS; r0 += max_rows) {
    int rows = (ROWS - r0 < max_rows) ? (ROWS - r0) : max_rows;
    hipLaunchKernelGGL(gemm1_mfma, dim3((rows / 128) * 32), dim3(256), 0, stream,
                       Xh, Xl, W1h, W1l, b1, hbuf, r0 / 128);
    hipLaunchKernelGGL(gemm2_kernel, dim3(rows / 32, 4), dim3(256), 0, stream,
                       hbuf, W2, Mpart, r0);
  }
  hipLaunchKernelGGL(sinkhorn_kernel, dim3(BATCH), dim3(64), 0, stream,
                     Mpart, b2, out_psi, out_X);
  hipLaunchKernelGGL(hungarian_kernel, dim3(BATCH), dim3(64), 0, stream,
                     Mpart, out_perms, out_dist);
}

// Round 3
// 584.746 us; speedup vs baseline: 1.2316x; 1.0482x over previous
//
#include <hip/hip_runtime.h>

// Problem constants
#define NMAT 50
#define BATCH 128
#define FDIM 1024
#define HDIM 4096
#define ROWS 6400            // BATCH*NMAT
#define PSIZE 320000         // BATCH*NMAT*NMAT
#define HINF 1e18

// ws layout (bytes):
//   Mpart : [0, 10240000)           fp64 [4][6400][50] split-K partials;
//                                   partial 0 overwritten with psi64 by sinkhorn
//   Xh/Xl : packed split-bf16 X     [50 mt][32 k0b][4 kg][128 m][8] each 13.1 MB
//   W1h/l : packed split-bf16 W1^T  [32 nt][32 k0b][4 kg][128 n][8] each 8.4 MB
//   hbuf  : fp32 [max_rows][4096]   chunked to fit remaining ws
#define WS_M_OFF   0
#define WS_XH_OFF  10240000LL
#define WS_XL_OFF  23347200LL
#define WS_W1H_OFF 36454400LL
#define WS_W1L_OFF 44843008LL
#define WS_H_OFF   53231616LL
#define WS_MIN     (WS_H_OFF + 128LL * HDIM * 4)   // ~55.3 MB

typedef __bf16 bf16x8 __attribute__((ext_vector_type(8)));
typedef float f32x4 __attribute__((ext_vector_type(4)));
typedef double f64x4 __attribute__((ext_vector_type(4)));
typedef unsigned short u16;

__device__ __forceinline__ float bf16_to_f32(unsigned short h) {
  return __uint_as_float(((unsigned int)h) << 16);
}
__device__ __forceinline__ unsigned short f32_to_bf16(float f) {
  unsigned int u = __float_as_uint(f);
  u += 0x7FFFu + ((u >> 16) & 1u);   // RNE
  return (unsigned short)(u >> 16);
}

// async global->LDS, 16B per lane; LDS dest = wave-uniform base + lane*16
__device__ __forceinline__ void gload16(const u16* g, u16* l) {
  __builtin_amdgcn_global_load_lds(
      (const __attribute__((address_space(1))) unsigned int*)g,
      (__attribute__((address_space(3))) unsigned int*)l, 16, 0, 0);
}

// ---------------- pre-pass: X fp32 -> packed split-bf16 ---------------------
// out layout: [mt][k0b][kg][m][8] elems; blockIdx = mt*32 + k0b.
__global__ __launch_bounds__(256) void convert_x(
    const float* __restrict__ X, u16* __restrict__ Xh, u16* __restrict__ Xl) {
  int t = threadIdx.x;
  int mt = blockIdx.x >> 5, k0b = blockIdx.x & 31;
  size_t outbase = (size_t)blockIdx.x * 4096;
#pragma unroll
  for (int it = 0; it < 2; ++it) {
    int idx = t + it * 256;
    int m = idx & 127, kg = idx >> 7;
    const float* src = X + (size_t)(mt * 128 + m) * FDIM + k0b * 32 + kg * 8;
    float4 v0 = *(const float4*)src;
    float4 v1 = *(const float4*)(src + 4);
    float f[8] = {v0.x, v0.y, v0.z, v0.w, v1.x, v1.y, v1.z, v1.w};
    unsigned short h[8], l[8];
#pragma unroll
    for (int j = 0; j < 8; ++j) {
      h[j] = f32_to_bf16(f[j]);
      l[j] = f32_to_bf16(f[j] - bf16_to_f32(h[j]));
    }
    uint4 hv, lv;
    hv.x = h[0] | ((unsigned)h[1] << 16); hv.y = h[2] | ((unsigned)h[3] << 16);
    hv.z = h[4] | ((unsigned)h[5] << 16); hv.w = h[6] | ((unsigned)h[7] << 16);
    lv.x = l[0] | ((unsigned)l[1] << 16); lv.y = l[2] | ((unsigned)l[3] << 16);
    lv.z = l[4] | ((unsigned)l[5] << 16); lv.w = l[6] | ((unsigned)l[7] << 16);
    size_t off = outbase + (size_t)(kg * 128 + m) * 8;
    *(uint4*)&Xh[off] = hv;
    *(uint4*)&Xl[off] = lv;
  }
}

// ---------------- pre-pass: W1 fp32 -> transposed packed split-bf16 ---------
// out layout: [nt][k0b][kg][n][8]; blockIdx = nt*32 + k0b.
__global__ __launch_bounds__(256) void convert_w1(
    const float* __restrict__ W1, u16* __restrict__ Wh, u16* __restrict__ Wl) {
  int t = threadIdx.x;
  int nt = blockIdx.x >> 5, k0b = blockIdx.x & 31;
  size_t outbase = (size_t)blockIdx.x * 4096;
#pragma unroll
  for (int it = 0; it < 2; ++it) {
    int idx = t + it * 256;
    int n = idx & 127, kg = idx >> 7;
    float f[8];
#pragma unroll
    for (int j = 0; j < 8; ++j)
      f[j] = W1[(size_t)(k0b * 32 + kg * 8 + j) * HDIM + nt * 128 + n];
    unsigned short h[8], l[8];
#pragma unroll
    for (int j = 0; j < 8; ++j) {
      h[j] = f32_to_bf16(f[j]);
      l[j] = f32_to_bf16(f[j] - bf16_to_f32(h[j]));
    }
    uint4 hv, lv;
    hv.x = h[0] | ((unsigned)h[1] << 16); hv.y = h[2] | ((unsigned)h[3] << 16);
    hv.z = h[4] | ((unsigned)h[5] << 16); hv.w = h[6] | ((unsigned)h[7] << 16);
    lv.x = l[0] | ((unsigned)l[1] << 16); lv.y = l[2] | ((unsigned)l[3] << 16);
    lv.z = l[4] | ((unsigned)l[5] << 16); lv.w = l[6] | ((unsigned)l[7] << 16);
    size_t off = outbase + (size_t)(kg * 128 + n) * 8;
    *(uint4*)&Wh[off] = hv;
    *(uint4*)&Wl[off] = lv;
  }
}

// ---------------- GEMM1 (split-bf16 MFMA): h = leaky(x @ W1 + b1) -----------
// Inputs pre-split/pre-packed; staging is pure global_load_lds width-16.
// 128x128 tile, BK=32, 4 waves, 48 MFMA per k-step.
__global__ __launch_bounds__(256) void gemm1_mfma(
    const u16* __restrict__ Ah_, const u16* __restrict__ Al_,
    const u16* __restrict__ Bh_, const u16* __restrict__ Bl_,
    const float* __restrict__ b1,
    float* __restrict__ Hout,          // chunk base [rows][4096] fp32
    int mt0) {                         // global m-tile offset of this chunk
  __shared__ __align__(16) u16 Ah[4096];
  __shared__ __align__(16) u16 Al[4096];
  __shared__ __align__(16) u16 Bh[4096];
  __shared__ __align__(16) u16 Bl[4096];
  int t = threadIdx.x;
  int wave = t >> 6, lane = t & 63;
  int nt = blockIdx.x & 31;      // 4096/128 n-tiles
  int mtl = blockIdx.x >> 5;     // m-tile local to chunk
  int wm = wave >> 1, wn = wave & 1;
  int fr = lane & 15, fg = lane >> 4;

  f32x4 acc[4][4];
#pragma unroll
  for (int i = 0; i < 4; ++i)
#pragma unroll
    for (int j = 0; j < 4; ++j) acc[i][j] = (f32x4){0.f, 0.f, 0.f, 0.f};

  const u16* pAh = Ah_ + (size_t)(mt0 + mtl) * 32 * 4096;
  const u16* pAl = Al_ + (size_t)(mt0 + mtl) * 32 * 4096;
  const u16* pBh = Bh_ + (size_t)nt * 32 * 4096;
  const u16* pBl = Bl_ + (size_t)nt * 32 * 4096;
  int so = wave * 1024 + lane * 8;   // per-lane src offset (elems), call 0
  int ld = wave * 1024;              // wave-uniform LDS dest (elems)

  for (int k0b = 0; k0b < 32; ++k0b) {
    __syncthreads();                 // previous-iter fragment reads done
    size_t sb = (size_t)k0b * 4096;
    gload16(pAh + sb + so,       &Ah[ld]);
    gload16(pAh + sb + so + 512, &Ah[ld + 512]);
    gload16(pAl + sb + so,       &Al[ld]);
    gload16(pAl + sb + so + 512, &Al[ld + 512]);
    gload16(pBh + sb + so,       &Bh[ld]);
    gload16(pBh + sb + so + 512, &Bh[ld + 512]);
    gload16(pBl + sb + so,       &Bl[ld]);
    gload16(pBl + sb + so + 512, &Bl[ld + 512]);
    __syncthreads();                 // vmcnt(0) drained by compiler before barrier
    // ---- fragments + MFMA ----
    bf16x8 ah[4], al[4], bh[4], bl[4];
#pragma unroll
    for (int i = 0; i < 4; ++i) {
      int arow = (fg * 128 + wm * 64 + i * 16 + fr) * 8;
      ah[i] = *(const bf16x8*)&Ah[arow];
      al[i] = *(const bf16x8*)&Al[arow];
      int brow = (fg * 128 + wn * 64 + i * 16 + fr) * 8;
      bh[i] = *(const bf16x8*)&Bh[brow];
      bl[i] = *(const bf16x8*)&Bl[brow];
    }
#pragma unroll
    for (int i = 0; i < 4; ++i)
#pragma unroll
      for (int j = 0; j < 4; ++j)
        acc[i][j] = __builtin_amdgcn_mfma_f32_16x16x32_bf16(ah[i], bh[j], acc[i][j], 0, 0, 0);
#pragma unroll
    for (int i = 0; i < 4; ++i)
#pragma unroll
      for (int j = 0; j < 4; ++j)
        acc[i][j] = __builtin_amdgcn_mfma_f32_16x16x32_bf16(ah[i], bl[j], acc[i][j], 0, 0, 0);
#pragma unroll
    for (int i = 0; i < 4; ++i)
#pragma unroll
      for (int j = 0; j < 4; ++j)
        acc[i][j] = __builtin_amdgcn_mfma_f32_16x16x32_bf16(al[i], bh[j], acc[i][j], 0, 0, 0);
  }

  // Epilogue: col=lane&15, row=(lane>>4)*4+reg [m89-verified]
  int colb = nt * 128 + wn * 64 + fr;
  int rowb = mtl * 128 + wm * 64 + fg * 4;
#pragma unroll
  for (int j = 0; j < 4; ++j) {
    float bias = b1[colb + j * 16];
#pragma unroll
    for (int i = 0; i < 4; ++i)
#pragma unroll
      for (int r = 0; r < 4; ++r) {
        float v = acc[i][j][r] + bias;
        v = v >= 0.0f ? v : 0.01f * v;
        Hout[(size_t)(rowb + i * 16 + r) * HDIM + colb + j * 16] = v;
      }
  }
}

// ---------------- GEMM2 (fp64 MFMA, layout self-calibrating) ----------------
// Round-2 failed with a Sinkhorn-flattened "scrambled-M" signature (psi absmax
// 2.7e-2): the ASSUMED v_mfma_f64_16x16x4 fragment layout is wrong on gfx950
// (the m89/m101 layout verification never covered f64). Fix: probe the real
// layout at runtime with 4 calibration MFMAs, then read fragments / scatter
// results through the probed maps. Correct for ANY D layout and for both
// plausible A/B operand maps (lane=16k+i vs lane=4i+k):
//   probe pA = mfma(lane, 1): D = sum_k laneidx_A(i,k); standard map gives
//     96+4i (==0 mod 4), k-fastest gives 16i+6 (==2 mod 4) -> 1 AND detects.
//   probe p1 = mfma(ai, 1): D[i][j] = 4i -> di[r] = exact row of acc reg r.
//   probe p2 = mfma(1, bj): D[i][j] = 4j -> dj[r] = exact col of acc reg r.
// Numerics: pure fp64 FMA accumulation (reassociation-only vs round-1 serial).
__global__ __launch_bounds__(256) void gemm2_mfma(
    const float* __restrict__ hchunk,        // chunk base [rows][4096] fp32
    const float* __restrict__ W2,            // [4096][50] fp32
    double* __restrict__ Mpart,              // [4][6400][50]
    int row0) {
  __shared__ __align__(16) float hs[64 * 68];
  __shared__ __align__(16) float w2s[64 * 68];
  int t = threadIdx.x;
  int wave = t >> 6, lane = t & 63;
  int kz = blockIdx.y;
  int fr = lane & 15, fk = lane >> 4;
  const float* hbase = hchunk + (size_t)blockIdx.x * 64 * HDIM;

  // ---- layout calibration (4 MFMAs, once per block) ----
  f64x4 z4 = (f64x4){0.0, 0.0, 0.0, 0.0};
  f64x4 pA = __builtin_amdgcn_mfma_f64_16x16x4f64((double)lane, 1.0, z4, 0, 0, 0);
  f64x4 pB = __builtin_amdgcn_mfma_f64_16x16x4f64(1.0, (double)lane, z4, 0, 0, 0);
  int aAlt = ((int)pA[0]) & 3;       // 0: lane=16k+i, nonzero: lane=4i+k
  int bAlt = ((int)pB[0]) & 3;
  int ai = aAlt ? (lane >> 2) : fr;  // this lane's A operand (row, k) indices
  int ak = aAlt ? (lane & 3) : fk;
  int bj = bAlt ? (lane >> 2) : fr;  // this lane's B operand (col, k) indices
  int bk = bAlt ? (lane & 3) : fk;
  f64x4 p1 = __builtin_amdgcn_mfma_f64_16x16x4f64((double)ai, 1.0, z4, 0, 0, 0);
  f64x4 p2 = __builtin_amdgcn_mfma_f64_16x16x4f64(1.0, (double)bj, z4, 0, 0, 0);
  int di[4], dj[4];
#pragma unroll
  for (int r = 0; r < 4; ++r) {
    di[r] = (((int)p1[r]) >> 2) & 15;   // exact output row of acc reg r
    dj[r] = (((int)p2[r]) >> 2) & 15;   // exact output col of acc reg r
  }

  f64x4 acc[4];
#pragma unroll
  for (int nt = 0; nt < 4; ++nt) acc[nt] = (f64x4){0.0, 0.0, 0.0, 0.0};

  for (int k0 = kz * 1024; k0 < kz * 1024 + 1024; k0 += 64) {
    __syncthreads();
    {  // stage h: 64 rows x 64 k, float4 x4 per thread, coalesced
      int row = t >> 2, seg = (t & 3) * 16;
      const float4* src = (const float4*)(hbase + (size_t)row * HDIM + k0 + seg);
      float4* dst = (float4*)&hs[row * 68 + seg];
      dst[0] = src[0]; dst[1] = src[1]; dst[2] = src[2]; dst[3] = src[3];
    }
    // stage W2: 64 k x 64 n (cols >= 50 zero-filled)
    for (int idx = t; idx < 64 * 64; idx += 256) {
      int kk = idx >> 6, n = idx & 63;
      w2s[kk * 68 + n] = (n < NMAT) ? W2[(size_t)(k0 + kk) * NMAT + n] : 0.0f;
    }
    __syncthreads();
#pragma unroll
    for (int kk = 0; kk < 64; kk += 4) {
      double av = (double)hs[(wave * 16 + ai) * 68 + kk + ak];
#pragma unroll
      for (int nt = 0; nt < 4; ++nt) {
        double bv = (double)w2s[(kk + bk) * 68 + nt * 16 + bj];
        acc[nt] = __builtin_amdgcn_mfma_f64_16x16x4f64(av, bv, acc[nt], 0, 0, 0);
      }
    }
  }
  double* Mout = Mpart + (size_t)kz * PSIZE;
  int rowbase = row0 + blockIdx.x * 64 + wave * 16;
#pragma unroll
  for (int nt = 0; nt < 4; ++nt)
#pragma unroll
    for (int r = 0; r < 4; ++r) {
      int col = nt * 16 + dj[r];
      if (col < NMAT)
        Mout[(size_t)(rowbase + di[r]) * NMAT + col] = acc[nt][r];
    }
}

// ---------------- Sinkhorn (fp64): merge 4 partials, P=exp(leaky(M+b2)), ----
// 5x row/col norm. Writes psi64 into Mpart[0] region (block-local, safe).
__global__ __launch_bounds__(64) void sinkhorn_kernel(
    double* __restrict__ Mpart, const float* __restrict__ b2,
    float* __restrict__ out_psi, float* __restrict__ out_X) {
  int b = blockIdx.x, lane = threadIdx.x;
  __shared__ double P[2500];
  __shared__ double rs[50];
  const size_t base = (size_t)b * 2500;
  for (int e = lane; e < 2500; e += 64) {
    double m = Mpart[base + e] + Mpart[PSIZE + base + e] +
               Mpart[2 * PSIZE + base + e] + Mpart[3 * PSIZE + base + e];
    m += (double)b2[e % 50];
    m = m >= 0.0 ? m : 0.01 * m;      // leaky_relu in fp64
    P[e] = exp(m);                    // TAU = 1.0
  }
  __syncthreads();
  for (int it = 0; it < 5; ++it) {
    if (lane < 50) { double s = 0; for (int j = 0; j < 50; ++j) s += P[lane * 50 + j]; rs[lane] = s; }
    __syncthreads();
    for (int e = lane; e < 2500; e += 64) P[e] /= rs[e / 50];   // axis=2
    __syncthreads();
    if (lane < 50) { double s = 0; for (int r = 0; r < 50; ++r) s += P[r * 50 + lane]; rs[lane] = s; }
    __syncthreads();
    for (int e = lane; e < 2500; e += 64) P[e] /= rs[e % 50];   // axis=1
    __syncthreads();
  }
  for (int e = lane; e < 2500; e += 64) {
    double pv = P[e];
    Mpart[base + e] = pv;             // psi64 in-place (partial-0 region)
    float f = (float)pv;
    out_psi[base + e] = f;
    out_X[base + e] = f;              // ALPHA=1.0 => X == psi exactly
  }
}

// ---------------- Hungarian (exact replica of the reference's algorithm, ----
// including its dead-minv behavior), fp64, one wave per batch. FP32 outputs.
__global__ __launch_bounds__(64) void hungarian_kernel(
    const double* __restrict__ psi64, float* __restrict__ out_perms,
    float* __restrict__ out_dist) {
  int b = blockIdx.x, lane = threadIdx.x;
  __shared__ double cost[2500];
  __shared__ double u[51];
  __shared__ int p[51];
  __shared__ int wayl[51];
  const double* P = psi64 + (size_t)b * 2500;
  for (int e = lane; e < 2500; e += 64) cost[e] = -P[e];
  if (lane < 51) { u[lane] = 0.0; p[lane] = 0; }
  __syncthreads();
  double v = 0.0;                      // v[lane+1]
  bool lactive = lane < NMAT;

  for (int i = 1; i <= NMAT; ++i) {
    bool used = false;
    int way = 0;
    int j0 = 0, j1 = 0;
    for (int guard = 0; guard < 64; ++guard) {   // defensive cap (normally <=51)
      if (lane == j0 - 1) used = true;           // used[j0] = True (j0>=1)
      int i0 = (j0 == 0) ? i : p[j0];
      double ui0 = u[i0];
      double cand = HINF;
      if (lactive && !used) {
        cand = cost[(i0 - 1) * NMAT + lane] - ui0 - v;
        way = j0;                                // way set for ALL free cols (dead-minv)
      }
      double m = cand;
#pragma unroll
      for (int s = 32; s > 0; s >>= 1) {
        double o = __shfl_xor(m, s, 64);
        m = (o < m) ? o : m;
      }
      unsigned long long bal = __ballot(cand == m);
      j1 = (int)__builtin_ctzll(bal) + 1;        // np.argmin tie-break: lowest j
      double delta = m;
      __syncthreads();
      if (used) { v -= delta; u[p[lane + 1]] += delta; }   // distinct rows, no race
      if (lane == 63) u[i] += delta;                       // j=0 column: p[0]=i
      __syncthreads();
      j0 = j1;
      if (p[j0] == 0) break;
    }
    if (lactive) wayl[lane + 1] = way;
    __syncthreads();
    if (lane == 0) {                   // augment (serial, path <= 50)
      int j = j1;
      while (j != 0) {
        int jw = wayl[j];
        p[j] = (jw == 0) ? i : p[jw];
        j = jw;
      }
    }
    __syncthreads();
  }

  // perms one-hot + dist (fp32 outputs)
  size_t pbase = (size_t)b * 2500;
  for (int e = lane; e < 2500; e += 64) out_perms[pbase + e] = 0.0f;
  __syncthreads();
  double val = 0.0;
  if (lactive) {
    int row = p[lane + 1] - 1;
    if (row < 0) row = 0;              // defensive clamp (provably unreachable)
    if (row > 49) row = 49;
    out_perms[pbase + (size_t)row * NMAT + lane] = 1.0f;
    val = P[(size_t)row * NMAT + lane];
  }
#pragma unroll
  for (int s = 32; s > 0; s >>= 1) val += __shfl_xor(val, s, 64);
  if (lane == 0) out_dist[b] = (float)(val / (double)NMAT);
}

// ---------------------------------------------------------------------------
extern "C" void kernel_launch(void* const* d_in, const int* in_sizes, int n_in,
                              void* d_out, int out_size, void* d_ws, size_t ws_size,
                              hipStream_t stream) {
  const float* x  = (const float*)d_in[0];   // fp32 per the reference dtypes
  const float* W1 = (const float*)d_in[1];
  const float* b1 = (const float*)d_in[2];
  const float* W2 = (const float*)d_in[3];
  const float* b2 = (const float*)d_in[4];
  float* out = (float*)d_out;                // outputs float32 (round-8/11 finding)
  float* out_psi   = out;
  float* out_perms = out + PSIZE;
  float* out_X     = out + 2 * PSIZE;
  float* out_dist  = out + 3 * PSIZE;

  if (ws_size < (size_t)WS_MIN) return;

  char* ws = (char*)d_ws;
  double* Mpart = (double*)(ws + WS_M_OFF);
  u16* Xh  = (u16*)(ws + WS_XH_OFF);
  u16* Xl  = (u16*)(ws + WS_XL_OFF);
  u16* W1h = (u16*)(ws + WS_W1H_OFF);
  u16* W1l = (u16*)(ws + WS_W1L_OFF);
  float* hbuf = (float*)(ws + WS_H_OFF);
  long long avail = (long long)ws_size - WS_H_OFF;
  int max_rows = (int)(avail / (HDIM * 4));
  max_rows = (max_rows / 128) * 128;
  if (max_rows > ROWS) max_rows = ROWS;

  // one-time split-bf16 conversion + packing (replaces per-k-step VALU work)
  hipLaunchKernelGGL(convert_x, dim3(1600), dim3(256), 0, stream, x, Xh, Xl);
  hipLaunchKernelGGL(convert_w1, dim3(1024), dim3(256), 0, stream, W1, W1h, W1l);

  for (int r0 = 0; r0 < ROWS; r0 += max_rows) {
    int rows = (ROWS - r0 < max_rows) ? (ROWS - r0) : max_rows;
    hipLaunchKernelGGL(gemm1_mfma, dim3((rows / 128) * 32), dim3(256), 0, stream,
                       Xh, Xl, W1h, W1l, b1, hbuf, r0 / 128);
    hipLaunchKernelGGL(gemm2_mfma, dim3(rows / 64, 4), dim3(256), 0, stream,
                       hbuf, W2, Mpart, r0);
  }
  hipLaunchKernelGGL(sinkhorn_kernel, dim3(BATCH), dim3(64), 0, stream,
                     Mpart, b2, out_psi, out_X);
  hipLaunchKernelGGL(hungarian_kernel, dim3(BATCH), dim3(64), 0, stream,
                     Mpart, out_perms, out_dist);
}

// Round 5
// 554.482 us; speedup vs baseline: 1.2989x; 1.0546x over previous
//
#include <hip/hip_runtime.h>

// Problem constants
#define NMAT 50
#define BATCH 128
#define FDIM 1024
#define HDIM 4096
#define ROWS 6400            // BATCH*NMAT
#define PSIZE 320000         // BATCH*NMAT*NMAT
#define HINF 1e18

// ws layout (bytes):
//   Mpart : [0, 10240000)           fp64 [4][6400][50] split-K partials
//   Xh/Xl : packed split-bf16 X     [50 mt][32 k0b][4 kg][128 m][8] each 13.1 MB
//   W1h/l : packed split-bf16 W1^T  [32 nt][32 k0b][4 kg][128 n][8] each 8.4 MB
//   hbuf  : fp32 [max_rows][4096]   chunked to fit remaining ws
#define WS_M_OFF   0
#define WS_XH_OFF  10240000LL
#define WS_XL_OFF  23347200LL
#define WS_W1H_OFF 36454400LL
#define WS_W1L_OFF 44843008LL
#define WS_H_OFF   53231616LL
#define WS_MIN     (WS_H_OFF + 128LL * HDIM * 4)   // ~55.3 MB

typedef __bf16 bf16x8 __attribute__((ext_vector_type(8)));
typedef float f32x4 __attribute__((ext_vector_type(4)));
typedef double f64x4 __attribute__((ext_vector_type(4)));
typedef unsigned short u16;

__device__ __forceinline__ float bf16_to_f32(unsigned short h) {
  return __uint_as_float(((unsigned int)h) << 16);
}
__device__ __forceinline__ unsigned short f32_to_bf16(float f) {
  unsigned int u = __float_as_uint(f);
  u += 0x7FFFu + ((u >> 16) & 1u);   // RNE
  return (unsigned short)(u >> 16);
}

// async global->LDS, 16B per lane; LDS dest = wave-uniform base + lane*16
__device__ __forceinline__ void gload16(const u16* g, u16* l) {
  __builtin_amdgcn_global_load_lds(
      (const __attribute__((address_space(1))) unsigned int*)g,
      (__attribute__((address_space(3))) unsigned int*)l, 16, 0, 0);
}

// ---- wave-wide fp64 min via DPP (VALU pipe, lower latency than the 6-level
// shfl_xor/LDS chain). row_shr:1/2/4/8 reduce within 16-lane rows,
// row_bcast15/31 combine rows; lane 63 ends with the full 64-lane min
// (canonical GCN reduction sequence, cf. rocPRIM). bound_ctrl=false keeps the
// old value on invalid lanes (min identity). DPP only permutes genuine lane
// values, so the result is always SOME lane's cand -> ballot non-empty.
__device__ __forceinline__ double wave_min_f64(double x) {
  union { double d; int i[2]; } u, t;
  u.d = x;
#define DPP_MIN_STEP(ctrl)                                                   \
  t.i[0] = __builtin_amdgcn_update_dpp(u.i[0], u.i[0], ctrl, 0xf, 0xf, false);\
  t.i[1] = __builtin_amdgcn_update_dpp(u.i[1], u.i[1], ctrl, 0xf, 0xf, false);\
  u.d = fmin(u.d, t.d);
  DPP_MIN_STEP(0x111)  // row_shr:1
  DPP_MIN_STEP(0x112)  // row_shr:2
  DPP_MIN_STEP(0x114)  // row_shr:4
  DPP_MIN_STEP(0x118)  // row_shr:8
  DPP_MIN_STEP(0x142)  // row_bcast15
  DPP_MIN_STEP(0x143)  // row_bcast31
#undef DPP_MIN_STEP
  union { double d; int i[2]; } r;
  r.i[0] = __builtin_amdgcn_readlane(u.i[0], 63);
  r.i[1] = __builtin_amdgcn_readlane(u.i[1], 63);
  return r.d;
}

// ---------------- pre-pass: X fp32 -> packed split-bf16 ---------------------
__global__ __launch_bounds__(256) void convert_x(
    const float* __restrict__ X, u16* __restrict__ Xh, u16* __restrict__ Xl) {
  int t = threadIdx.x;
  int mt = blockIdx.x >> 5, k0b = blockIdx.x & 31;
  size_t outbase = (size_t)blockIdx.x * 4096;
#pragma unroll
  for (int it = 0; it < 2; ++it) {
    int idx = t + it * 256;
    int m = idx & 127, kg = idx >> 7;
    const float* src = X + (size_t)(mt * 128 + m) * FDIM + k0b * 32 + kg * 8;
    float4 v0 = *(const float4*)src;
    float4 v1 = *(const float4*)(src + 4);
    float f[8] = {v0.x, v0.y, v0.z, v0.w, v1.x, v1.y, v1.z, v1.w};
    unsigned short h[8], l[8];
#pragma unroll
    for (int j = 0; j < 8; ++j) {
      h[j] = f32_to_bf16(f[j]);
      l[j] = f32_to_bf16(f[j] - bf16_to_f32(h[j]));
    }
    uint4 hv, lv;
    hv.x = h[0] | ((unsigned)h[1] << 16); hv.y = h[2] | ((unsigned)h[3] << 16);
    hv.z = h[4] | ((unsigned)h[5] << 16); hv.w = h[6] | ((unsigned)h[7] << 16);
    lv.x = l[0] | ((unsigned)l[1] << 16); lv.y = l[2] | ((unsigned)l[3] << 16);
    lv.z = l[4] | ((unsigned)l[5] << 16); lv.w = l[6] | ((unsigned)l[7] << 16);
    size_t off = outbase + (size_t)(kg * 128 + m) * 8;
    *(uint4*)&Xh[off] = hv;
    *(uint4*)&Xl[off] = lv;
  }
}

// ---------------- pre-pass: W1 fp32 -> transposed packed split-bf16 ---------
__global__ __launch_bounds__(256) void convert_w1(
    const float* __restrict__ W1, u16* __restrict__ Wh, u16* __restrict__ Wl) {
  int t = threadIdx.x;
  int nt = blockIdx.x >> 5, k0b = blockIdx.x & 31;
  size_t outbase = (size_t)blockIdx.x * 4096;
#pragma unroll
  for (int it = 0; it < 2; ++it) {
    int idx = t + it * 256;
    int n = idx & 127, kg = idx >> 7;
    float f[8];
#pragma unroll
    for (int j = 0; j < 8; ++j)
      f[j] = W1[(size_t)(k0b * 32 + kg * 8 + j) * HDIM + nt * 128 + n];
    unsigned short h[8], l[8];
#pragma unroll
    for (int j = 0; j < 8; ++j) {
      h[j] = f32_to_bf16(f[j]);
      l[j] = f32_to_bf16(f[j] - bf16_to_f32(h[j]));
    }
    uint4 hv, lv;
    hv.x = h[0] | ((unsigned)h[1] << 16); hv.y = h[2] | ((unsigned)h[3] << 16);
    hv.z = h[4] | ((unsigned)h[5] << 16); hv.w = h[6] | ((unsigned)h[7] << 16);
    lv.x = l[0] | ((unsigned)l[1] << 16); lv.y = l[2] | ((unsigned)l[3] << 16);
    lv.z = l[4] | ((unsigned)l[5] << 16); lv.w = l[6] | ((unsigned)l[7] << 16);
    size_t off = outbase + (size_t)(kg * 128 + n) * 8;
    *(uint4*)&Wh[off] = hv;
    *(uint4*)&Wl[off] = lv;
  }
}

// ---------------- GEMM1 (split-bf16 MFMA): h = leaky(x @ W1 + b1) -----------
// 128x128 tile, BK=32, 4 waves, 48 MFMA per k-step; staging via
// global_load_lds width-16 only. At 937 TF (m97-structure ceiling).
__global__ __launch_bounds__(256) void gemm1_mfma(
    const u16* __restrict__ Ah_, const u16* __restrict__ Al_,
    const u16* __restrict__ Bh_, const u16* __restrict__ Bl_,
    const float* __restrict__ b1,
    float* __restrict__ Hout,          // chunk base [rows][4096] fp32
    int mt0) {                         // global m-tile offset of this chunk
  __shared__ __align__(16) u16 Ah[4096];
  __shared__ __align__(16) u16 Al[4096];
  __shared__ __align__(16) u16 Bh[4096];
  __shared__ __align__(16) u16 Bl[4096];
  int t = threadIdx.x;
  int wave = t >> 6, lane = t & 63;
  int nt = blockIdx.x & 31;      // 4096/128 n-tiles
  int mtl = blockIdx.x >> 5;     // m-tile local to chunk
  int wm = wave >> 1, wn = wave & 1;
  int fr = lane & 15, fg = lane >> 4;

  f32x4 acc[4][4];
#pragma unroll
  for (int i = 0; i < 4; ++i)
#pragma unroll
    for (int j = 0; j < 4; ++j) acc[i][j] = (f32x4){0.f, 0.f, 0.f, 0.f};

  const u16* pAh = Ah_ + (size_t)(mt0 + mtl) * 32 * 4096;
  const u16* pAl = Al_ + (size_t)(mt0 + mtl) * 32 * 4096;
  const u16* pBh = Bh_ + (size_t)nt * 32 * 4096;
  const u16* pBl = Bl_ + (size_t)nt * 32 * 4096;
  int so = wave * 1024 + lane * 8;   // per-lane src offset (elems), call 0
  int ld = wave * 1024;              // wave-uniform LDS dest (elems)

  for (int k0b = 0; k0b < 32; ++k0b) {
    __syncthreads();                 // previous-iter fragment reads done
    size_t sb = (size_t)k0b * 4096;
    gload16(pAh + sb + so,       &Ah[ld]);
    gload16(pAh + sb + so + 512, &Ah[ld + 512]);
    gload16(pAl + sb + so,       &Al[ld]);
    gload16(pAl + sb + so + 512, &Al[ld + 512]);
    gload16(pBh + sb + so,       &Bh[ld]);
    gload16(pBh + sb + so + 512, &Bh[ld + 512]);
    gload16(pBl + sb + so,       &Bl[ld]);
    gload16(pBl + sb + so + 512, &Bl[ld + 512]);
    __syncthreads();                 // vmcnt(0) drained by compiler before barrier
    // ---- fragments + MFMA ----
    bf16x8 ah[4], al[4], bh[4], bl[4];
#pragma unroll
    for (int i = 0; i < 4; ++i) {
      int arow = (fg * 128 + wm * 64 + i * 16 + fr) * 8;
      ah[i] = *(const bf16x8*)&Ah[arow];
      al[i] = *(const bf16x8*)&Al[arow];
      int brow = (fg * 128 + wn * 64 + i * 16 + fr) * 8;
      bh[i] = *(const bf16x8*)&Bh[brow];
      bl[i] = *(const bf16x8*)&Bl[brow];
    }
#pragma unroll
    for (int i = 0; i < 4; ++i)
#pragma unroll
      for (int j = 0; j < 4; ++j)
        acc[i][j] = __builtin_amdgcn_mfma_f32_16x16x32_bf16(ah[i], bh[j], acc[i][j], 0, 0, 0);
#pragma unroll
    for (int i = 0; i < 4; ++i)
#pragma unroll
      for (int j = 0; j < 4; ++j)
        acc[i][j] = __builtin_amdgcn_mfma_f32_16x16x32_bf16(ah[i], bl[j], acc[i][j], 0, 0, 0);
#pragma unroll
    for (int i = 0; i < 4; ++i)
#pragma unroll
      for (int j = 0; j < 4; ++j)
        acc[i][j] = __builtin_amdgcn_mfma_f32_16x16x32_bf16(al[i], bh[j], acc[i][j], 0, 0, 0);
  }

  // Epilogue: col=lane&15, row=(lane>>4)*4+reg [m89-verified]
  int colb = nt * 128 + wn * 64 + fr;
  int rowb = mtl * 128 + wm * 64 + fg * 4;
#pragma unroll
  for (int j = 0; j < 4; ++j) {
    float bias = b1[colb + j * 16];
#pragma unroll
    for (int i = 0; i < 4; ++i)
#pragma unroll
      for (int r = 0; r < 4; ++r) {
        float v = acc[i][j][r] + bias;
        v = v >= 0.0f ? v : 0.01f * v;
        Hout[(size_t)(rowb + i * 16 + r) * HDIM + colb + j * 16] = v;
      }
  }
}

// ---------------- GEMM2 (fp64 MFMA, layout self-calibrating) ----------------
// Self-calibrates the v_mfma_f64_16x16x4 fragment layout at runtime (4 probe
// MFMAs) — correct for ANY A/B/D layout (round-3 verified, absmax 2.44e-4).
// Round-5 (=4) change: DUAL accumulator sets (even/odd kk-groups) -> 8
// independent MFMA chains per wave instead of 4, to cover f64-MFMA latency.
// fp64 reassociation only (~1e-15).
__global__ __launch_bounds__(256) void gemm2_mfma(
    const float* __restrict__ hchunk,        // chunk base [rows][4096] fp32
    const float* __restrict__ W2,            // [4096][50] fp32
    double* __restrict__ Mpart,              // [4][6400][50]
    int row0) {
  __shared__ __align__(16) float hs[64 * 68];
  __shared__ __align__(16) float w2s[64 * 68];
  int t = threadIdx.x;
  int wave = t >> 6, lane = t & 63;
  int kz = blockIdx.y;
  int fr = lane & 15, fk = lane >> 4;
  const float* hbase = hchunk + (size_t)blockIdx.x * 64 * HDIM;

  // ---- layout calibration (4 MFMAs, once per block) ----
  f64x4 z4 = (f64x4){0.0, 0.0, 0.0, 0.0};
  f64x4 pA = __builtin_amdgcn_mfma_f64_16x16x4f64((double)lane, 1.0, z4, 0, 0, 0);
  f64x4 pB = __builtin_amdgcn_mfma_f64_16x16x4f64(1.0, (double)lane, z4, 0, 0, 0);
  int aAlt = ((int)pA[0]) & 3;       // 0: lane=16k+i, nonzero: lane=4i+k
  int bAlt = ((int)pB[0]) & 3;
  int ai = aAlt ? (lane >> 2) : fr;  // this lane's A operand (row, k) indices
  int ak = aAlt ? (lane & 3) : fk;
  int bj = bAlt ? (lane >> 2) : fr;  // this lane's B operand (col, k) indices
  int bk = bAlt ? (lane & 3) : fk;
  f64x4 p1 = __builtin_amdgcn_mfma_f64_16x16x4f64((double)ai, 1.0, z4, 0, 0, 0);
  f64x4 p2 = __builtin_amdgcn_mfma_f64_16x16x4f64(1.0, (double)bj, z4, 0, 0, 0);
  int di[4], dj[4];
#pragma unroll
  for (int r = 0; r < 4; ++r) {
    di[r] = (((int)p1[r]) >> 2) & 15;   // exact output row of acc reg r
    dj[r] = (((int)p2[r]) >> 2) & 15;   // exact output col of acc reg r
  }

  f64x4 acc[4], acc2[4];
#pragma unroll
  for (int nt = 0; nt < 4; ++nt) { acc[nt] = z4; acc2[nt] = z4; }

  int arow = (wave * 16 + ai) * 68 + ak;
  for (int k0 = kz * 1024; k0 < kz * 1024 + 1024; k0 += 64) {
    __syncthreads();
    {  // stage h: 64 rows x 64 k, float4 x4 per thread, coalesced
      int row = t >> 2, seg = (t & 3) * 16;
      const float4* src = (const float4*)(hbase + (size_t)row * HDIM + k0 + seg);
      float4* dst = (float4*)&hs[row * 68 + seg];
      dst[0] = src[0]; dst[1] = src[1]; dst[2] = src[2]; dst[3] = src[3];
    }
    // stage W2: 64 k x 64 n (cols >= 50 zero-filled)
    for (int idx = t; idx < 64 * 64; idx += 256) {
      int kk = idx >> 6, n = idx & 63;
      w2s[kk * 68 + n] = (n < NMAT) ? W2[(size_t)(k0 + kk) * NMAT + n] : 0.0f;
    }
    __syncthreads();
#pragma unroll
    for (int kk = 0; kk < 64; kk += 8) {
      double av0 = (double)hs[arow + kk];
      double av1 = (double)hs[arow + kk + 4];
#pragma unroll
      for (int nt = 0; nt < 4; ++nt) {
        double bv = (double)w2s[(kk + bk) * 68 + nt * 16 + bj];
        acc[nt] = __builtin_amdgcn_mfma_f64_16x16x4f64(av0, bv, acc[nt], 0, 0, 0);
      }
#pragma unroll
      for (int nt = 0; nt < 4; ++nt) {
        double bv = (double)w2s[(kk + 4 + bk) * 68 + nt * 16 + bj];
        acc2[nt] = __builtin_amdgcn_mfma_f64_16x16x4f64(av1, bv, acc2[nt], 0, 0, 0);
      }
    }
  }
  double* Mout = Mpart + (size_t)kz * PSIZE;
  int rowbase = row0 + blockIdx.x * 64 + wave * 16;
#pragma unroll
  for (int nt = 0; nt < 4; ++nt) {
    f64x4 s = acc[nt] + acc2[nt];
#pragma unroll
    for (int r = 0; r < 4; ++r) {
      int col = nt * 16 + dj[r];
      if (col < NMAT)
        Mout[(size_t)(rowbase + di[r]) * NMAT + col] = s[r];
    }
  }
}

// ---------------- Fused Sinkhorn + Hungarian (fp64, one wave per batch) -----
// Sinkhorn: merge 4 partials, P = exp(leaky(M+b2)), 5x row/col norm (all in
// LDS). Hungarian runs directly on the LDS P (no psi64 global round-trip).
// Hungarian is an exact replica of the reference algorithm (incl. dead-minv);
// min-reduce via DPP (wave_min_f64) — identical fp64 min value, identical
// lowest-j ballot tie-break. Augment loop bounded (defensive; path <= 50).
__global__ __launch_bounds__(64) void sinkhorn_hungarian(
    const double* __restrict__ Mpart, const float* __restrict__ b2,
    float* __restrict__ out_psi, float* __restrict__ out_X,
    float* __restrict__ out_perms, float* __restrict__ out_dist) {
  int b = blockIdx.x, lane = threadIdx.x;
  __shared__ double P[2500];
  __shared__ double cost[2500];
  __shared__ double rs[50];
  __shared__ double u[51];
  __shared__ int p[51];
  __shared__ int wayl[51];
  const size_t base = (size_t)b * 2500;

  // ---- Sinkhorn ----
  for (int e = lane; e < 2500; e += 64) {
    double m = Mpart[base + e] + Mpart[PSIZE + base + e] +
               Mpart[2 * PSIZE + base + e] + Mpart[3 * PSIZE + base + e];
    m += (double)b2[e % 50];
    m = m >= 0.0 ? m : 0.01 * m;      // leaky_relu in fp64
    P[e] = exp(m);                    // TAU = 1.0
  }
  __syncthreads();
  for (int it = 0; it < 5; ++it) {
    if (lane < 50) { double s = 0; for (int j = 0; j < 50; ++j) s += P[lane * 50 + j]; rs[lane] = s; }
    __syncthreads();
    for (int e = lane; e < 2500; e += 64) P[e] /= rs[e / 50];   // axis=2
    __syncthreads();
    if (lane < 50) { double s = 0; for (int r = 0; r < 50; ++r) s += P[r * 50 + lane]; rs[lane] = s; }
    __syncthreads();
    for (int e = lane; e < 2500; e += 64) P[e] /= rs[e % 50];   // axis=1
    __syncthreads();
  }
  for (int e = lane; e < 2500; e += 64) {
    float f = (float)P[e];
    out_psi[base + e] = f;
    out_X[base + e] = f;              // ALPHA=1.0 => X == psi exactly
    cost[e] = -P[e];
  }
  if (lane < 51) { u[lane] = 0.0; p[lane] = 0; }
  __syncthreads();

  // ---- Hungarian ----
  double v = 0.0;                      // v[lane+1]
  bool lactive = lane < NMAT;
  for (int i = 1; i <= NMAT; ++i) {
    bool used = false;
    int way = 0;
    int j0 = 0, j1 = 0;
    for (int guard = 0; guard < 64; ++guard) {   // defensive cap (normally <=51)
      if (lane == j0 - 1) used = true;           // used[j0] = True (j0>=1)
      int i0 = (j0 == 0) ? i : p[j0];
      double ui0 = u[i0];
      double cand = HINF;
      if (lactive && !used) {
        cand = cost[(i0 - 1) * NMAT + lane] - ui0 - v;
        way = j0;                                // way set for ALL free cols (dead-minv)
      }
      double m = wave_min_f64(cand);
      unsigned long long bal = __ballot(cand == m);
      j1 = (int)__builtin_ctzll(bal) + 1;        // np.argmin tie-break: lowest j
      double delta = m;
      __syncthreads();
      if (used) { v -= delta; u[p[lane + 1]] += delta; }   // distinct rows, no race
      if (lane == 63) u[i] += delta;                       // j=0 column: p[0]=i
      __syncthreads();
      j0 = j1;
      if (p[j0] == 0) break;
    }
    if (lactive) wayl[lane + 1] = way;
    __syncthreads();
    if (lane == 0) {                   // augment (serial; path <= 50, bounded)
      int j = j1;
      for (int step = 0; step < 64 && j != 0; ++step) {
        int jw = wayl[j];
        p[j] = (jw == 0) ? i : p[jw];
        j = jw;
      }
    }
    __syncthreads();
  }

  // perms one-hot + dist (fp32 outputs)
  size_t pbase = (size_t)b * 2500;
  for (int e = lane; e < 2500; e += 64) out_perms[pbase + e] = 0.0f;
  __syncthreads();
  double val = 0.0;
  if (lactive) {
    int row = p[lane + 1] - 1;
    if (row < 0) row = 0;              // defensive clamp (provably unreachable)
    if (row > 49) row = 49;
    out_perms[pbase + (size_t)row * NMAT + lane] = 1.0f;
    val = P[(size_t)row * NMAT + lane];
  }
#pragma unroll
  for (int s = 32; s > 0; s >>= 1) val += __shfl_xor(val, s, 64);
  if (lane == 0) out_dist[b] = (float)(val / (double)NMAT);
}

// ---------------------------------------------------------------------------
extern "C" void kernel_launch(void* const* d_in, const int* in_sizes, int n_in,
                              void* d_out, int out_size, void* d_ws, size_t ws_size,
                              hipStream_t stream) {
  const float* x  = (const float*)d_in[0];   // fp32 per the reference dtypes
  const float* W1 = (const float*)d_in[1];
  const float* b1 = (const float*)d_in[2];
  const float* W2 = (const float*)d_in[3];
  const float* b2 = (const float*)d_in[4];
  float* out = (float*)d_out;                // outputs float32 (round-8/11 finding)
  float* out_psi   = out;
  float* out_perms = out + PSIZE;
  float* out_X     = out + 2 * PSIZE;
  float* out_dist  = out + 3 * PSIZE;

  if (ws_size < (size_t)WS_MIN) return;

  char* ws = (char*)d_ws;
  double* Mpart = (double*)(ws + WS_M_OFF);
  u16* Xh  = (u16*)(ws + WS_XH_OFF);
  u16* Xl  = (u16*)(ws + WS_XL_OFF);
  u16* W1h = (u16*)(ws + WS_W1H_OFF);
  u16* W1l = (u16*)(ws + WS_W1L_OFF);
  float* hbuf = (float*)(ws + WS_H_OFF);
  long long avail = (long long)ws_size - WS_H_OFF;
  int max_rows = (int)(avail / (HDIM * 4));
  max_rows = (max_rows / 128) * 128;
  if (max_rows > ROWS) max_rows = ROWS;

  // one-time split-bf16 conversion + packing (replaces per-k-step VALU work)
  hipLaunchKernelGGL(convert_x, dim3(1600), dim3(256), 0, stream, x, Xh, Xl);
  hipLaunchKernelGGL(convert_w1, dim3(1024), dim3(256), 0, stream, W1, W1h, W1l);

  for (int r0 = 0; r0 < ROWS; r0 += max_rows) {
    int rows = (ROWS - r0 < max_rows) ? (ROWS - r0) : max_rows;
    hipLaunchKernelGGL(gemm1_mfma, dim3((rows / 128) * 32), dim3(256), 0, stream,
                       Xh, Xl, W1h, W1l, b1, hbuf, r0 / 128);
    hipLaunchKernelGGL(gemm2_mfma, dim3(rows / 64, 4), dim3(256), 0, stream,
                       hbuf, W2, Mpart, r0);
  }
  hipLaunchKernelGGL(sinkhorn_hungarian, dim3(BATCH), dim3(64), 0, stream,
                     Mpart, b2, out_psi, out_X, out_perms, out_dist);
}